// Round 6
// baseline (10412.569 us; speedup 1.0000x reference)
//
#include <hip/hip_runtime.h>

// ESN forward, teacher-forced: s[t] = tanh(w@s[t-1] + w_in@in[t] + w_fb@out[t-1]) + 1e-3*(nu[t]-0.5)
// Persistent kernel, 128 blocks x 256 threads, 16 rows/block, W in LDS (128KB).
//
// Round-6 experiment: TEST the coherence-op-throughput hypothesis.
// Evidence so far: 8x MORE publish ops (replication) => -70% perf; 8x FEWER
// lines per op (strided polls) => only +5%. So the fabric appears to charge
// per 8B agent-scope OP, not per line. Poll ops/step = NBLK * 2048 * sweeps.
// Halving NBLK (256->128) halves poll ops; per-thread FMA doubles (cheap,
// VALU is 13% busy). Also: FMA-as-ready -- dot-product folded into the poll
// retry loop under predication, so compute overlaps detect and the post-
// detect tail is just the last word's FMAs + reduce.
//
// Kept from rounds 4-5: W in LDS ([rr][cc][tid][j] 16B-lane-stride layout,
// 0 bank conflicts measured), pre-poll ds_read prefetch + asm memory fence
// (lgkmcnt independent of poll vmcnt), {fp32,tag} fused 8B words at agent
// scope double-buffered by parity, strided ownership, s_sleep(1) pacing,
// fast tanh (exp2+rcp).

#define N_RES   2048
#define N_IN    64
#define N_OUT   32
#define T_STEPS 4096
#define NOISEC  0.001f
#define NBLK    128
#define NTHR    256
#define RPB     16    // rows per block
#define CPT     8     // state words (cols) per thread, stride NTHR

typedef float f32x4 __attribute__((ext_vector_type(4)));

__device__ __forceinline__ float fast_tanh(float x) {
    // tanh(x) = 1 - 2/(e^{2x}+1);  e^{2x} = exp2(2*log2(e)*x)
    const float e = __builtin_amdgcn_exp2f(2.8853900818f * x);
    return fmaf(-2.f, __builtin_amdgcn_rcpf(e + 1.f), 1.f);
}

__global__ void esn_init(unsigned long long* __restrict__ slots) {
    const int i = blockIdx.x * blockDim.x + threadIdx.x;
    if (i < 2 * N_RES)
        __hip_atomic_store(slots + i, 0ull, __ATOMIC_RELAXED, __HIP_MEMORY_SCOPE_AGENT);
}

__global__ __launch_bounds__(NTHR, 1)
void esn_run(const float* __restrict__ inputs,    // T x 64
             const float* __restrict__ outputs,   // T x 32
             const float* __restrict__ w,         // 2048 x 2048
             const float* __restrict__ w_in,      // 2048 x 64
             const float* __restrict__ w_feedb,   // 2048 x 32
             const float* __restrict__ out_w,     // 32 x 2048
             const float* __restrict__ out_b,     // 32
             const float* __restrict__ noise_u,   // T x 2048
             float* __restrict__ d_out,           // 32 + 2048
             unsigned long long* __restrict__ slots) { // 2 x 2048 tagged words
    const int tid  = threadIdx.x;
    const int blk  = blockIdx.x;
    const int row0 = blk * RPB;
    const int wav  = tid >> 6;
    const int lan  = tid & 63;

    // [rr][cc][tid][j]: element (row = rr*4+j, col = cc*256+tid). 128KB.
    __shared__ float wlds[4 * 8 * NTHR * 4];
    __shared__ float red[2][4][RPB];

    // ---- one-time: stage my block's 16 W rows into LDS (coalesced) ----
    #pragma unroll
    for (int r = 0; r < RPB; ++r)
        #pragma unroll
        for (int cc = 0; cc < 8; ++cc) {
            const float v = w[(size_t)(row0 + r) * N_RES + cc * NTHR + tid];
            wlds[(((r >> 2) * 8 + cc) * NTHR + tid) * 4 + (r & 3)] = v;
        }
    // w_in / w_feedb: one virtual column per thread (tid<96)
    float wex[RPB];
    #pragma unroll
    for (int r = 0; r < RPB; ++r) {
        float v = 0.f;
        if (tid < N_IN)              v = w_in[(row0 + r) * N_IN + tid];
        else if (tid < N_IN + N_OUT) v = w_feedb[(row0 + r) * N_OUT + (tid - N_IN)];
        wex[r] = v;
    }
    __syncthreads();

    for (int t = 1; t < T_STEPS; ++t) {
        const unsigned need = (unsigned)(t - 1);
        const unsigned long long* sl = slots + (size_t)((t - 1) & 1) * N_RES + tid;

        // ---- issue the first poll sweep early (long-latency vmcnt path) ----
        unsigned long long vv[CPT];
        #pragma unroll
        for (int i = 0; i < CPT; ++i)
            vv[i] = __hip_atomic_load(sl + i * NTHR, __ATOMIC_RELAXED, __HIP_MEMORY_SCOPE_AGENT);

        // off-critical-path operands (overlap with poll latency)
        float xv = 0.f;
        if (tid < N_IN)              xv = inputs[t * N_IN + tid];
        else if (tid < N_IN + N_OUT) xv = outputs[(t - 1) * N_OUT + (tid - N_IN)];
        float nu = 0.f;
        if (tid < RPB) nu = noise_u[(size_t)t * N_RES + row0 + tid];

        // ---- prefetch W fragment from LDS (state-independent) ----
        f32x4 wv[32];
        #pragma unroll
        for (int rr = 0; rr < 4; ++rr)
            #pragma unroll
            for (int cc = 0; cc < 8; ++cc)
                wv[rr * 8 + cc] = *reinterpret_cast<const f32x4*>(
                    &wlds[((rr * 8 + cc) * NTHR + tid) * 4]);

        // fence: nothing above may sink below (ds_reads ride out the poll on
        // the independent lgkmcnt counter)
        asm volatile("" ::: "memory");

        // ---- poll with FMA-as-ready: each fresh word's 16 FMAs execute
        //      under predication while stale words are re-fetched ----
        float acc[RPB];
        #pragma unroll
        for (int r = 0; r < RPB; ++r) acc[r] = 0.f;
        unsigned done = 0;
        for (;;) {
            unsigned fresh = 0;
            #pragma unroll
            for (int i = 0; i < CPT; ++i)
                if (!((done >> i) & 1) && (unsigned)(vv[i] >> 32) >= need)
                    fresh |= 1u << i;
            #pragma unroll
            for (int i = 0; i < CPT; ++i)
                if ((fresh >> i) & 1) {
                    const float sv = __uint_as_float((unsigned)(vv[i] & 0xffffffffu));
                    #pragma unroll
                    for (int rr = 0; rr < 4; ++rr)
                        #pragma unroll
                        for (int j = 0; j < 4; ++j)
                            acc[rr * 4 + j] = fmaf(wv[rr * 8 + i][j], sv, acc[rr * 4 + j]);
                }
            done |= fresh;
            if (done == 0xffu) break;
            __builtin_amdgcn_s_sleep(1);   // pace the retry (op-rate relief)
            #pragma unroll
            for (int i = 0; i < CPT; ++i)
                if (!((done >> i) & 1))
                    vv[i] = __hip_atomic_load(sl + i * NTHR, __ATOMIC_RELAXED, __HIP_MEMORY_SCOPE_AGENT);
        }
        #pragma unroll
        for (int r = 0; r < RPB; ++r) acc[r] = fmaf(wex[r], xv, acc[r]);

        // ---- wave reduce: halving exchange (1,2,4) then butterfly (8,16,32) ----
        {   const bool b = (lan & 1);
            #pragma unroll
            for (int r = 0; r < 8; ++r) {
                const float send = b ? acc[r] : acc[r + 8];
                const float got  = __shfl_xor(send, 1, 64);
                acc[r] = (b ? acc[r + 8] : acc[r]) + got;
            }
        }
        {   const bool b = (lan >> 1) & 1;
            #pragma unroll
            for (int r = 0; r < 4; ++r) {
                const float send = b ? acc[r] : acc[r + 4];
                const float got  = __shfl_xor(send, 2, 64);
                acc[r] = (b ? acc[r + 4] : acc[r]) + got;
            }
        }
        {   const bool b = (lan >> 2) & 1;
            #pragma unroll
            for (int r = 0; r < 2; ++r) {
                const float send = b ? acc[r] : acc[r + 2];
                const float got  = __shfl_xor(send, 4, 64);
                acc[r] = (b ? acc[r + 2] : acc[r]) + got;
            }
        }
        #pragma unroll
        for (int m = 8; m < 64; m <<= 1) {
            acc[0] += __shfl_xor(acc[0], m, 64);
            acc[1] += __shfl_xor(acc[1], m, 64);
        }
        // lane l (l<8) holds rows rb, rb+1 with rb = 8*b0 + 4*b1 + 2*b2
        if (lan < 8) {
            const int rb = 8 * (lan & 1) + 4 * ((lan >> 1) & 1) + 2 * ((lan >> 2) & 1);
            red[t & 1][wav][rb]     = acc[0];
            red[t & 1][wav][rb + 1] = acc[1];
        }
        __syncthreads();

        // ---- wave 0, lanes 0-15: final sum + tanh + publish (2 lines) ----
        if (tid < RPB) {
            const float tot = red[t & 1][0][tid] + red[t & 1][1][tid]
                            + red[t & 1][2][tid] + red[t & 1][3][tid];
            const float val = fast_tanh(tot) + NOISEC * (nu - 0.5f);
            const unsigned long long pk =
                ((unsigned long long)(unsigned)t << 32) |
                (unsigned long long)__float_as_uint(val);
            __hip_atomic_store(slots + (size_t)(t & 1) * N_RES + row0 + tid, pk,
                               __ATOMIC_RELAXED, __HIP_MEMORY_SCOPE_AGENT);
            if (t == T_STEPS - 1) d_out[32 + row0 + tid] = val;
        }
        // no second barrier: red[] double-buffered by t&1; any wave's next
        // write to this buffer parity is behind the t+1 barrier.
    }

    // ---- epilogue: block 0 computes readout = out_w @ s_final + out_b ----
    if (blk == 0) {
        const unsigned long long* sf = slots + (size_t)((T_STEPS - 1) & 1) * N_RES;
        const int r2 = tid >> 3, j2 = tid & 7;     // 32 rows x 8 lanes
        const unsigned need = (unsigned)(T_STEPS - 1);
        float acc = 0.f;
        for (int c0 = 0; c0 < N_RES / 8; c0 += 8) { // 256 cols/lane, 8 at a time
            const unsigned long long* p = sf + j2 * (N_RES / 8) + c0;
            unsigned long long vv[8];
            #pragma unroll
            for (int i = 0; i < 8; ++i)
                vv[i] = __hip_atomic_load(p + i, __ATOMIC_RELAXED, __HIP_MEMORY_SCOPE_AGENT);
            for (;;) {
                unsigned mn = 0xffffffffu;
                #pragma unroll
                for (int i = 0; i < 8; ++i) {
                    const unsigned tg = (unsigned)(vv[i] >> 32);
                    mn = (tg < mn) ? tg : mn;
                }
                if (mn >= need) break;
                __builtin_amdgcn_s_sleep(1);
                #pragma unroll
                for (int i = 0; i < 8; ++i)
                    if ((unsigned)(vv[i] >> 32) < need)
                        vv[i] = __hip_atomic_load(p + i, __ATOMIC_RELAXED, __HIP_MEMORY_SCOPE_AGENT);
            }
            #pragma unroll
            for (int i = 0; i < 8; ++i) {
                const float sv = __uint_as_float((unsigned)(vv[i] & 0xffffffffu));
                acc = fmaf(out_w[r2 * N_RES + j2 * (N_RES / 8) + c0 + i], sv, acc);
            }
        }
        #pragma unroll
        for (int m = 1; m < 8; m <<= 1) acc += __shfl_xor(acc, m, 64);
        if (j2 == 0) d_out[r2] = acc + out_b[r2];
    }
}

extern "C" void kernel_launch(void* const* d_in, const int* in_sizes, int n_in,
                              void* d_out, int out_size, void* d_ws, size_t ws_size,
                              hipStream_t stream) {
    const float* inputs  = (const float*)d_in[0];
    const float* outputs = (const float*)d_in[1];
    const float* w       = (const float*)d_in[2];
    const float* w_in    = (const float*)d_in[3];
    const float* w_feedb = (const float*)d_in[4];
    const float* out_w   = (const float*)d_in[5];
    const float* out_b   = (const float*)d_in[6];
    const float* noise_u = (const float*)d_in[7];
    unsigned long long* slots = (unsigned long long*)d_ws; // 2 x 2048 x 8B = 32 KB

    // re-init tags every call (d_ws is not re-poisoned between graph replays)
    esn_init<<<(2 * N_RES + NTHR - 1) / NTHR, NTHR, 0, stream>>>(slots);
    esn_run<<<NBLK, NTHR, 0, stream>>>(inputs, outputs, w, w_in, w_feedb,
                                       out_w, out_b, noise_u,
                                       (float*)d_out, slots);
}